// Round 7
// baseline (379.410 us; speedup 1.0000x reference)
//
#include <hip/hip_runtime.h>
#include <hip/hip_bf16.h>
#include <math.h>

#define N_VOTERS 1048576
#define NUM_CAND 32
#define EMB 128
#define NUM_ELEC 4096

typedef unsigned short u16;
typedef unsigned int u32;
typedef __attribute__((ext_vector_type(8))) short bf16x8;
typedef __attribute__((ext_vector_type(4))) short short4v;
typedef __attribute__((ext_vector_type(4))) float f32x4;

#if defined(__has_builtin)
#if __has_builtin(__builtin_amdgcn_cvt_pk_bf16_f32)
#define HAVE_CVT_PK_BF16 1
#endif
#endif

__device__ __forceinline__ u16 f2bf(float f) {   // RNE (prep only)
    union { float f; u32 u; } v; v.f = f;
    u32 r = v.u + 0x7FFFu + ((v.u >> 16) & 1u);
    return (u16)(r >> 16);
}
// pack two floats to bf16: f0 -> low16, f1 -> high16.
__device__ __forceinline__ u32 pk2(float f0, float f1) {
#ifdef HAVE_CVT_PK_BF16
    typedef __attribute__((ext_vector_type(2))) __bf16 bf16x2;
    bf16x2 r = __builtin_amdgcn_cvt_pk_bf16_f32(f0, f1);   // lo=cvt(f0), hi=cvt(f1)
    union { bf16x2 v; u32 u; } c; c.v = r;
    return c.u;
#else
    u32 u0 = __float_as_uint(f0) + 0x8000u;
    u32 u1 = __float_as_uint(f1) + 0x8000u;
    return __builtin_amdgcn_perm(u1, u0, 0x07060302u);
#endif
}

// ---------------- Kernel A: transpose+convert local weights to bf16 ----------------
// w1t: [128][32] = W1^T (out-major); w2t/w3t: [128][128] (out-major) — A-frag layout.
__global__ void prep_weights(const float* __restrict__ lW1, const float* __restrict__ lW2,
                             const float* __restrict__ lW3,
                             u16* __restrict__ w1t, u16* __restrict__ w2t, u16* __restrict__ w3t) {
    int tid = blockIdx.x * blockDim.x + threadIdx.x;  // 0..16383
    if (tid < 4096) {
        int n = tid >> 5, k = tid & 31;
        w1t[tid] = f2bf(lW1[k * EMB + n]);
    }
    {
        int n = tid >> 7, k = tid & 127;
        w2t[tid] = f2bf(lW2[k * EMB + n]);
        w3t[tid] = f2bf(lW3[k * EMB + n]);
    }
}

// ---------------- Kernel B: fused local MLP, grid-stride groups, resident weights -------
// 2048 blocks x 256 thr (4 waves). Wave wv owns features wv*32..+31 for L1/L2.
// R17 DIAGNOSIS (from R10/R16 counter arithmetic): the kernel is LDS-PIPE-BOUND —
// ds_read_b128 act traffic alone is 41us of R10's 122us (82us of R16's 149us: doubling
// waves doubled act reads and REGRESSED despite occupancy 29->42%). Total act-read bytes
// = act_bytes x (128 / feats-per-wave); 32 feats/wave is the register-feasible floor, so
// the only cut is deleting one act round-trip -> R14's L2+L3 linearity fusion (act2 and
// its barrier GONE, ~-45% LDS traffic). R14's dataflow PASSED; it died of spill at the
// (256,3)=170 cap (persistent 112 + transients ~170+, WRITE 274MB scratch).
// R17: __launch_bounds__(256, 2) -> 256-reg budget, peak ~170 fits with slack; spill
// structurally impossible. Occupancy 8 waves/CU is ACCEPTABLE because the machine is
// LDS-bound, not latency-bound. Fused nt-loop at unroll 1 to halve transients.
// FUSION: each wave computes the PARTIAL L3 product over its own k-slice (its L2 output,
// still in registers, redistributed C-layout -> B-frag via 8 shfl + 4 selects) for ALL
// 128 output features; the 4 waves' partials sum inside the existing atomics.
// ONE barrier per group (act1 double-buffered for the WAR fence).
// R11/R12 (do not retry): direct per-lane global x loads spill. R13: setprio null.
// R16 (do not retry): 8-wave feature split doubles act reads = regression.
// Bias1/2 ride the MFMA C operand. Layer-3 partials C-chain across subtiles AND groups;
// flush = butterfly over 16 voter lanes + l15==0 atomics (8 m-tiles wide). Bias3
// deferred via per-election voter counts.
__global__ __launch_bounds__(256, 2) void local_fused(
    const float* __restrict__ x, const int* __restrict__ idx,
    const float* __restrict__ lb1, const float* __restrict__ lb2,
    const u16* __restrict__ w1t, const u16* __restrict__ w2t, const u16* __restrict__ w3t,
    float* __restrict__ agg, float* __restrict__ cntf)
{
    constexpr int XSTR = 36;   // x tile stride (72B rows, 8B-aligned b64 reads)
    constexpr int ASTR = 136;  // act stride (272B rows, 16B-aligned b128 reads)
    __shared__ __align__(16) u16 bufX[2][64 * XSTR];  // 2 x 4608 B
    __shared__ __align__(16) u16 act1[2][64 * ASTR];  // 2 x 17408 B  (total 44032)

    const int tid = threadIdx.x;
    const int lane = tid & 63;
    const int wv = tid >> 6;        // feature quarter 0..3 (L1/L2 slice, L3 k-slice)
    const int qd = lane >> 4;
    const int l15 = lane & 15;
    const int f0 = wv * 32;
    const int vbase = blockIdx.x * 512;

    // ---- weights + biases resident for the whole block ----
    // w1a/w2a: A-frags for the wave's OUT slice (rows f0.., k all).
    // w3n: A-frags for ALL 128 out rows, k restricted to the wave's slice f0..f0+31.
    bf16x8 w1a[2], w2a[2][4], w3n[8];
    f32x4 b1f[2], b2f[2];
    #pragma unroll
    for (int mt = 0; mt < 2; ++mt) {
        int mrow = f0 + mt * 16 + l15;
        w1a[mt] = *(const bf16x8*)(w1t + mrow * 32 + qd * 8);
        #pragma unroll
        for (int kk = 0; kk < 4; ++kk)
            w2a[mt][kk] = *(const bf16x8*)(w2t + mrow * 128 + kk * 32 + qd * 8);
        b1f[mt] = *(const f32x4*)(lb1 + f0 + mt * 16 + qd * 4);
        b2f[mt] = *(const f32x4*)(lb2 + f0 + mt * 16 + qd * 4);
    }
    #pragma unroll
    for (int mt = 0; mt < 8; ++mt)
        w3n[mt] = *(const bf16x8*)(w3t + (mt * 16 + l15) * 128 + f0 + qd * 8);

    // ---- segment state (spans all 8 groups): partial L3 sums for ALL 128 features ----
    f32x4 accR[8];
    #pragma unroll
    for (int mt = 0; mt < 8; ++mt) accR[mt] = (f32x4){0.f, 0.f, 0.f, 0.f};
    float cntv = 0.f;
    int cur = idx[vbase];

    auto flush = [&]() {   // wave-uniform call sites only
        #pragma unroll
        for (int d = 1; d < 16; d <<= 1)
            #pragma unroll
            for (int mt = 0; mt < 8; ++mt)
                #pragma unroll
                for (int r = 0; r < 4; ++r) accR[mt][r] += __shfl_xor(accR[mt][r], d, 16);
        if (l15 == 0) {
            float* p = agg + (size_t)cur * EMB + qd * 4;   // feature = mt*16 + qd*4 + r
            #pragma unroll
            for (int mt = 0; mt < 8; ++mt)
                #pragma unroll
                for (int r = 0; r < 4; ++r) atomicAdd(p + mt * 16 + r, accR[mt][r]);
            if (wv == 0 && qd == 0) atomicAdd(cntf + cur, cntv);
        }
        #pragma unroll
        for (int mt = 0; mt < 8; ++mt) accR[mt] = (f32x4){0.f, 0.f, 0.f, 0.f};
        cntv = 0.f;
    };

    auto loadx = [&](int v0, uint2* xp) {   // coalesced read + pack of one 64-voter tile
        const float4* xg = (const float4*)(x + (size_t)v0 * NUM_CAND);
        #pragma unroll
        for (int i = 0; i < 2; ++i) {
            float4 v = xg[i * 256 + tid];
            xp[i].x = pk2(v.x, v.y); xp[i].y = pk2(v.z, v.w);
        }
    };
    auto stagex = [&](u16* dst, const uint2* xp) {
        #pragma unroll
        for (int i = 0; i < 2; ++i) {
            int F = i * 256 + tid, row = F >> 3, c4 = (F & 7) * 4;
            *(uint2*)(dst + row * XSTR + c4) = xp[i];
        }
    };

    // ---- prologue: stage group 0, prefetch group 1 into regs ----
    uint2 xp[2];
    loadx(vbase, xp);
    stagex(bufX[0], xp);
    loadx(vbase + 64, xp);
    __syncthreads();                       // initial: bufX[0] visible

    #pragma unroll 1
    for (int g = 0; g < 8; ++g) {
        const int vg = vbase + g * 64;

        // hoist this group's segment ids (latency overlaps L1 compute)
        int sgv[4];
        #pragma unroll
        for (int nt = 0; nt < 4; ++nt) sgv[nt] = idx[vg + nt * 16 + l15];

        // ---- layer 1 (K=32): bufX[g&1] -> act1[g&1], bias in C, relu ----
        const u16* bx = bufX[g & 1];
        u16* a1w = act1[g & 1];
        #pragma unroll
        for (int nt = 0; nt < 4; ++nt) {
            int vr = nt * 16 + l15;
            union { bf16x8 v; short4v h[2]; } b;
            b.h[0] = *(const short4v*)(bx + vr * XSTR + qd * 8);
            b.h[1] = *(const short4v*)(bx + vr * XSTR + qd * 8 + 4);
            u16* wr = a1w + vr * ASTR + f0 + qd * 4;
            #pragma unroll
            for (int mt = 0; mt < 2; ++mt) {
                f32x4 a = __builtin_amdgcn_mfma_f32_16x16x32_bf16(w1a[mt], b.v, b1f[mt], 0, 0, 0);
                uint2 s;
                s.x = pk2(fmaxf(a[0], 0.f), fmaxf(a[1], 0.f));
                s.y = pk2(fmaxf(a[2], 0.f), fmaxf(a[3], 0.f));
                *(uint2*)(wr + mt * 16) = s;
            }
        }
        // stage bufX for g+1 (other buffer, no conflict); refill regs for g+2
        if (g < 7) stagex(bufX[(g + 1) & 1], xp);
        if (g < 6) loadx(vg + 128, xp);
        __syncthreads();                   // ONE barrier/group: act1[g&1] + bufX[(g+1)&1]

        // ---- fused layer 2+3 (per 16-voter subtile) ----
        const u16* a1r = act1[g & 1];
        #pragma unroll 1
        for (int nt = 0; nt < 4; ++nt) {
            // L2 (K=128): act1 -> regs, bias in C, relu
            const u16* rd = a1r + (nt * 16 + l15) * ASTR + qd * 8;
            bf16x8 B2[4];
            #pragma unroll
            for (int kk = 0; kk < 4; ++kk) B2[kk] = *(const bf16x8*)(rd + kk * 32);
            f32x4 a0 = b2f[0], a1v = b2f[1];
            #pragma unroll
            for (int kk = 0; kk < 4; ++kk)
                a0 = __builtin_amdgcn_mfma_f32_16x16x32_bf16(w2a[0][kk], B2[kk], a0, 0, 0, 0);
            #pragma unroll
            for (int kk = 0; kk < 4; ++kk)
                a1v = __builtin_amdgcn_mfma_f32_16x16x32_bf16(w2a[1][kk], B2[kk], a1v, 0, 0, 0);
            // relu+pack the wave's act2 slice: p0..p3 = rows f0+{qd*4+0,1 / +2,3 / 16+qd*4+0,1 / +2,3}
            u32 p0 = pk2(fmaxf(a0[0], 0.f),  fmaxf(a0[1], 0.f));
            u32 p1 = pk2(fmaxf(a0[2], 0.f),  fmaxf(a0[3], 0.f));
            u32 p2 = pk2(fmaxf(a1v[0], 0.f), fmaxf(a1v[1], 0.f));
            u32 p3 = pk2(fmaxf(a1v[2], 0.f), fmaxf(a1v[3], 0.f));
            // redistribute C-layout -> B-frag layout within each 16-lane column group:
            // target lane (qd,l15) word w holds k_local = qd*8+2w,+2w+1 for voter l15.
            // src lane A = ((2qd)&3)*16+l15 (w=0,1), src lane B = ((2qd+1)&3)*16+l15 (w=2,3);
            // src reg = p{w&1} for qd<2 (m-tile 0), p{2+(w&1)} for qd>=2 (m-tile 1).
            int lA = ((2 * qd) & 3) * 16 + l15;
            int lB = ((2 * qd + 1) & 3) * 16 + l15;
            u32 a0s = __shfl(p0, lA, 64), a1s = __shfl(p1, lA, 64);
            u32 a2s = __shfl(p2, lA, 64), a3s = __shfl(p3, lA, 64);
            u32 b0s = __shfl(p0, lB, 64), b1s = __shfl(p1, lB, 64);
            u32 b2s = __shfl(p2, lB, 64), b3s = __shfl(p3, lB, 64);
            bool lo = (qd < 2);
            union { bf16x8 v; u32 w[4]; } B3;
            B3.w[0] = lo ? a0s : a2s;
            B3.w[1] = lo ? a1s : a3s;
            B3.w[2] = lo ? b0s : b2s;
            B3.w[3] = lo ? b1s : b3s;

            // L3 partial (K=32, this wave's k-slice) -> accR via C-chaining
            int sg = sgv[nt];
            int first = __builtin_amdgcn_readfirstlane(sg);
            bool uni = (__ballot(sg == first) == ~0ull);
            if (uni) {
                if (first != cur) {
                    if (cntv > 0.f) flush();
                    cur = first;
                }
                #pragma unroll
                for (int mt = 0; mt < 8; ++mt)
                    accR[mt] = __builtin_amdgcn_mfma_f32_16x16x32_bf16(w3n[mt], B3.v, accR[mt], 0, 0, 0);
                cntv += 16.f;
            } else {                       // boundary inside subtile (rare)
                if (cntv > 0.f) flush();
                // segmented inclusive scan over 16 voter lanes (sorted -> masking safe)
                float one = 1.f;
                #pragma unroll
                for (int d = 1; d < 16; d <<= 1) {
                    int so = __shfl_up(sg, d, 16);
                    bool ok = (l15 >= d) && (so == sg);
                    float oc = __shfl_up(one, d, 16);
                    if (ok) one += oc;
                }
                int sgn = __shfl_down(sg, 1, 16);
                bool isend = (l15 == 15) || (sgn != sg);
                // two halves of 4 m-tiles to bound transient registers
                #pragma unroll
                for (int h = 0; h < 2; ++h) {
                    f32x4 D[4];
                    #pragma unroll
                    for (int m4 = 0; m4 < 4; ++m4) {
                        f32x4 z = {0.f, 0.f, 0.f, 0.f};
                        D[m4] = __builtin_amdgcn_mfma_f32_16x16x32_bf16(w3n[h * 4 + m4], B3.v, z, 0, 0, 0);
                    }
                    #pragma unroll
                    for (int d = 1; d < 16; d <<= 1) {
                        int so = __shfl_up(sg, d, 16);
                        bool ok = (l15 >= d) && (so == sg);
                        #pragma unroll
                        for (int m4 = 0; m4 < 4; ++m4)
                            #pragma unroll
                            for (int r = 0; r < 4; ++r) {
                                float o = __shfl_up(D[m4][r], d, 16);
                                if (ok) D[m4][r] += o;
                            }
                    }
                    if (isend) {
                        float* p = agg + (size_t)sg * EMB + h * 64 + qd * 4;
                        #pragma unroll
                        for (int m4 = 0; m4 < 4; ++m4)
                            #pragma unroll
                            for (int r = 0; r < 4; ++r) atomicAdd(p + m4 * 16 + r, D[m4][r]);
                    }
                }
                if (isend && wv == 0 && qd == 0) atomicAdd(cntf + sg, one);
                cur = __shfl(sg, 15, 16);  // last voter's run continues
            }
        }
    }
    if (cntv > 0.f) flush();
}

// ---------------- Kernel C: global MLP + log_softmax (fp32) ----------------
// Adds deferred local bias3: agg_true[s][j] = agg[s][j] + cnt[s]*lb3[j].
__global__ void __launch_bounds__(256) global_mlp(
    const float* __restrict__ agg, const float* __restrict__ cntf, const float* __restrict__ lb3,
    const float* __restrict__ gW1, const float* __restrict__ gb1,
    const float* __restrict__ gW2, const float* __restrict__ gb2,
    const float* __restrict__ gW3, const float* __restrict__ gb3,
    float* __restrict__ out)
{
    __shared__ float actA[8 * 128];
    __shared__ float actB[8 * 128];
    __shared__ float sc[8 * 32];
    const int tid = threadIdx.x;
    const int s0 = blockIdx.x * 8;

    #pragma unroll
    for (int i = 0; i < 4; ++i) {
        int f = i * 256 + tid;
        actA[f] = agg[(size_t)s0 * 128 + f] + cntf[s0 + (f >> 7)] * lb3[f & 127];
    }
    __syncthreads();

    const int j = tid & 127, g = tid >> 7;
    {
        float acc[4];
        #pragma unroll
        for (int si = 0; si < 4; ++si) acc[si] = gb1[j];
        #pragma unroll 8
        for (int k = 0; k < 128; ++k) {
            float w = gW1[k * 128 + j];
            #pragma unroll
            for (int si = 0; si < 4; ++si) acc[si] += actA[(g * 4 + si) * 128 + k] * w;
        }
        #pragma unroll
        for (int si = 0; si < 4; ++si) actB[(g * 4 + si) * 128 + j] = fmaxf(acc[si], 0.f);
    }
    __syncthreads();
    {
        float acc[4];
        #pragma unroll
        for (int si = 0; si < 4; ++si) acc[si] = gb2[j];
        #pragma unroll 8
        for (int k = 0; k < 128; ++k) {
            float w = gW2[k * 128 + j];
            #pragma unroll
            for (int si = 0; si < 4; ++si) acc[si] += actB[(g * 4 + si) * 128 + k] * w;
        }
        #pragma unroll
        for (int si = 0; si < 4; ++si) actA[(g * 4 + si) * 128 + j] = fmaxf(acc[si], 0.f);
    }
    __syncthreads();
    {
        int c = tid & 31, sg = tid >> 5;
        float a3 = gb3[c];
        #pragma unroll 8
        for (int k = 0; k < 128; ++k) a3 += actA[sg * 128 + k] * gW3[k * 32 + c];
        sc[sg * 32 + c] = a3;
    }
    __syncthreads();
    {
        int c = tid & 31, sg = tid >> 5;
        float v = sc[sg * 32 + c];
        float m = v;
        #pragma unroll
        for (int off = 16; off >= 1; off >>= 1) m = fmaxf(m, __shfl_xor(m, off, 32));
        float e = expf(v - m);
        float sum = e;
        #pragma unroll
        for (int off = 16; off >= 1; off >>= 1) sum += __shfl_xor(sum, off, 32);
        out[(size_t)(s0 + sg) * 32 + c] = (v - m) - logf(sum);
    }
}

extern "C" void kernel_launch(void* const* d_in, const int* in_sizes, int n_in,
                              void* d_out, int out_size, void* d_ws, size_t ws_size,
                              hipStream_t stream) {
    const float* x   = (const float*)d_in[0];
    const int*   idx = (const int*)d_in[1];
    const float* lW1 = (const float*)d_in[2];
    const float* lb1 = (const float*)d_in[3];
    const float* lW2 = (const float*)d_in[4];
    const float* lb2 = (const float*)d_in[5];
    const float* lW3 = (const float*)d_in[6];
    const float* lb3 = (const float*)d_in[7];
    const float* gW1 = (const float*)d_in[8];
    const float* gb1 = (const float*)d_in[9];
    const float* gW2 = (const float*)d_in[10];
    const float* gb2 = (const float*)d_in[11];
    const float* gW3 = (const float*)d_in[12];
    const float* gb3 = (const float*)d_in[13];
    float* out = (float*)d_out;

    float* agg  = (float*)d_ws;                                 // [4096][128] fp32 = 2 MB
    float* cntf = agg + (size_t)NUM_ELEC * EMB;                 // [4096] fp32
    u16* w1t = (u16*)(cntf + NUM_ELEC);
    u16* w2t = w1t + 128 * 32;
    u16* w3t = w2t + 128 * 128;

    hipMemsetAsync(d_ws, 0, ((size_t)NUM_ELEC * EMB + NUM_ELEC) * sizeof(float), stream);
    prep_weights<<<64, 256, 0, stream>>>(lW1, lW2, lW3, w1t, w2t, w3t);
    local_fused<<<N_VOTERS / 512, 256, 0, stream>>>(x, idx, lb1, lb2, w1t, w2t, w3t, agg, cntf);
    global_mlp<<<NUM_ELEC / 8, 256, 0, stream>>>(agg, cntf, lb3, gW1, gb1, gW2, gb2, gW3, gb3, out);
}

// Round 8
// 319.383 us; speedup vs baseline: 1.1879x; 1.1879x over previous
//
#include <hip/hip_runtime.h>
#include <hip/hip_bf16.h>
#include <math.h>

#define N_VOTERS 1048576
#define NUM_CAND 32
#define EMB 128
#define NUM_ELEC 4096

typedef unsigned short u16;
typedef unsigned int u32;
typedef __attribute__((ext_vector_type(8))) short bf16x8;
typedef __attribute__((ext_vector_type(4))) short short4v;
typedef __attribute__((ext_vector_type(4))) float f32x4;

#if defined(__has_builtin)
#if __has_builtin(__builtin_amdgcn_cvt_pk_bf16_f32)
#define HAVE_CVT_PK_BF16 1
#endif
#endif

__device__ __forceinline__ u16 f2bf(float f) {   // RNE (prep only)
    union { float f; u32 u; } v; v.f = f;
    u32 r = v.u + 0x7FFFu + ((v.u >> 16) & 1u);
    return (u16)(r >> 16);
}
// pack two floats to bf16: f0 -> low16, f1 -> high16.
__device__ __forceinline__ u32 pk2(float f0, float f1) {
#ifdef HAVE_CVT_PK_BF16
    typedef __attribute__((ext_vector_type(2))) __bf16 bf16x2;
    bf16x2 r = __builtin_amdgcn_cvt_pk_bf16_f32(f0, f1);   // lo=cvt(f0), hi=cvt(f1)
    union { bf16x2 v; u32 u; } c; c.v = r;
    return c.u;
#else
    u32 u0 = __float_as_uint(f0) + 0x8000u;
    u32 u1 = __float_as_uint(f1) + 0x8000u;
    return __builtin_amdgcn_perm(u1, u0, 0x07060302u);
#endif
}

// ---------------- Kernel A: transpose+convert local weights to bf16 ----------------
// w1t: [128][32] = W1^T (out-major); w2t/w3t: [128][128] (out-major) — A-frag layout.
__global__ void prep_weights(const float* __restrict__ lW1, const float* __restrict__ lW2,
                             const float* __restrict__ lW3,
                             u16* __restrict__ w1t, u16* __restrict__ w2t, u16* __restrict__ w3t) {
    int tid = blockIdx.x * blockDim.x + threadIdx.x;  // 0..16383
    if (tid < 4096) {
        int n = tid >> 5, k = tid & 31;
        w1t[tid] = f2bf(lW1[k * EMB + n]);
    }
    {
        int n = tid >> 7, k = tid & 127;
        w2t[tid] = f2bf(lW2[k * EMB + n]);
        w3t[tid] = f2bf(lW3[k * EMB + n]);
    }
}

// ---------------- Kernel B: fused local MLP, grid-stride groups, resident weights -------
// 2048 blocks x 256 thr (4 waves). Wave wv owns features wv*32..+31 (2 m-tiles); weights +
// biases resident in VGPRs.
// R18: VBLK 64 -> 128. Evidence: 3->2 barriers/group was -33us (155->122, R10) => barrier
// drains are ~2us each, ~30-40us of the 122us kernel. Doubling the voter tile halves
// barriers/voter: 4 groups x 2 barriers = 8/block (was 16), 2x MFMA per barrier.
// Enablers: (a) bufX double-buffer DELETED — stagex sits between B_b and B_c, after all
// L1 reads (pre-B_b) and before any L1(g+1) read (post-B_c), so a single buffer is
// race-free under the same 2 barriers; (b) LDS = 9216 + 2x34816 = 78848 B -> 2 blocks/CU
// (157.7 of 160 KiB). Occupancy 12 -> 8 waves/CU: ACCEPTABLE — R16 proved extra waves
// don't help (machine is LDS/barrier-bound, not latency-bound).
// __launch_bounds__(256,2): 256-reg budget removes spill pressure; LDS sets occupancy.
// TRIPWIRES: FETCH>150MB = remat (R9); WRITE>50MB = spill (R11/R14/R17); dur>=122us =>
// revert to R10 verbatim, plateau established.
// CLOSED (do not retry): L2+L3 linearity fusion (R14/R17: accR[8]+w3n[8] spills at ANY
// cap); direct per-lane global x loads (R11/R12); 8-wave feature split (R16: 2x act
// reads); s_setprio (R13: null); occupancy via launch_bounds relaxation (R15).
// Bias1/2 ride the MFMA C operand. Layer-3 C-operand chains the segment sum across
// subtiles AND groups; flush = butterfly over 16 voter lanes + l15==0 atomics. Bias3
// deferred via per-election voter counts.
__global__ __launch_bounds__(256, 2) void local_fused(
    const float* __restrict__ x, const int* __restrict__ idx,
    const float* __restrict__ lb1, const float* __restrict__ lb2,
    const u16* __restrict__ w1t, const u16* __restrict__ w2t, const u16* __restrict__ w3t,
    float* __restrict__ agg, float* __restrict__ cntf)
{
    constexpr int XSTR = 36;   // x tile stride (72B rows, 8B-aligned b64 reads)
    constexpr int ASTR = 136;  // act stride (272B rows, 16B-aligned b128 reads)
    constexpr int VBLK = 128;  // voters per group (R18: was 64)
    __shared__ __align__(16) u16 bufX[VBLK * XSTR];   // 9216 B (single buffer)
    __shared__ __align__(16) u16 act1[VBLK * ASTR];   // 34816 B
    __shared__ __align__(16) u16 act2[VBLK * ASTR];   // 34816 B  (total 78848)

    const int tid = threadIdx.x;
    const int lane = tid & 63;
    const int wv = tid >> 6;        // feature quarter 0..3
    const int qd = lane >> 4;
    const int l15 = lane & 15;
    const int f0 = wv * 32;
    const int vbase = blockIdx.x * 512;

    // ---- weights + biases resident for the whole block ----
    bf16x8 w1a[2], w2a[2][4], w3a[2][4];
    f32x4 b1f[2], b2f[2];
    #pragma unroll
    for (int mt = 0; mt < 2; ++mt) {
        int mrow = f0 + mt * 16 + l15;
        w1a[mt] = *(const bf16x8*)(w1t + mrow * 32 + qd * 8);
        #pragma unroll
        for (int kk = 0; kk < 4; ++kk) {
            w2a[mt][kk] = *(const bf16x8*)(w2t + mrow * 128 + kk * 32 + qd * 8);
            w3a[mt][kk] = *(const bf16x8*)(w3t + mrow * 128 + kk * 32 + qd * 8);
        }
        b1f[mt] = *(const f32x4*)(lb1 + f0 + mt * 16 + qd * 4);
        b2f[mt] = *(const f32x4*)(lb2 + f0 + mt * 16 + qd * 4);
    }

    // ---- segment state (spans all 4 groups) ----
    f32x4 accR[2];
    #pragma unroll
    for (int mt = 0; mt < 2; ++mt) accR[mt] = (f32x4){0.f, 0.f, 0.f, 0.f};
    float cntv = 0.f;
    int cur = idx[vbase];

    auto flush = [&]() {   // wave-uniform call sites only
        #pragma unroll
        for (int d = 1; d < 16; d <<= 1)
            #pragma unroll
            for (int mt = 0; mt < 2; ++mt)
                #pragma unroll
                for (int r = 0; r < 4; ++r) accR[mt][r] += __shfl_xor(accR[mt][r], d, 16);
        if (l15 == 0) {
            float* p = agg + (size_t)cur * EMB + f0 + qd * 4;
            #pragma unroll
            for (int mt = 0; mt < 2; ++mt)
                #pragma unroll
                for (int r = 0; r < 4; ++r) atomicAdd(p + mt * 16 + r, accR[mt][r]);
            if (wv == 0 && qd == 0) atomicAdd(cntf + cur, cntv);
        }
        #pragma unroll
        for (int mt = 0; mt < 2; ++mt) accR[mt] = (f32x4){0.f, 0.f, 0.f, 0.f};
        cntv = 0.f;
    };

    auto loadx = [&](int v0, uint2* xp) {   // coalesced read + pack of one 128-voter tile
        const float4* xg = (const float4*)(x + (size_t)v0 * NUM_CAND);
        #pragma unroll
        for (int i = 0; i < 4; ++i) {
            float4 v = xg[i * 256 + tid];
            xp[i].x = pk2(v.x, v.y); xp[i].y = pk2(v.z, v.w);
        }
    };
    auto stagex = [&](u16* dst, const uint2* xp) {
        #pragma unroll
        for (int i = 0; i < 4; ++i) {
            int F = i * 256 + tid, row = F >> 3, c4 = (F & 7) * 4;
            *(uint2*)(dst + row * XSTR + c4) = xp[i];
        }
    };

    // ---- prologue: stage group 0, prefetch group 1 into regs ----
    uint2 xp[4];
    loadx(vbase, xp);
    stagex(bufX, xp);
    loadx(vbase + VBLK, xp);
    __syncthreads();                       // initial: bufX visible

    #pragma unroll 1
    for (int g = 0; g < 4; ++g) {
        const int vg = vbase + g * VBLK;

        // hoist this group's segment ids (latency overlaps L1/L2 compute)
        int sgv[8];
        #pragma unroll
        for (int nt = 0; nt < 8; ++nt) sgv[nt] = idx[vg + nt * 16 + l15];

        // ---- layer 1 (K=32): bufX -> act1, bias in C, relu ----
        #pragma unroll
        for (int nt = 0; nt < 8; ++nt) {
            int vr = nt * 16 + l15;
            union { bf16x8 v; short4v h[2]; } b;
            b.h[0] = *(const short4v*)(bufX + vr * XSTR + qd * 8);
            b.h[1] = *(const short4v*)(bufX + vr * XSTR + qd * 8 + 4);
            u16* wr = act1 + vr * ASTR + f0 + qd * 4;
            #pragma unroll
            for (int mt = 0; mt < 2; ++mt) {
                f32x4 a = __builtin_amdgcn_mfma_f32_16x16x32_bf16(w1a[mt], b.v, b1f[mt], 0, 0, 0);
                uint2 s;
                s.x = pk2(fmaxf(a[0], 0.f), fmaxf(a[1], 0.f));
                s.y = pk2(fmaxf(a[2], 0.f), fmaxf(a[3], 0.f));
                *(uint2*)(wr + mt * 16) = s;
            }
        }
        __syncthreads();                   // B_b: act1 visible; bufX reads done

        // ---- restage bufX for g+1 from regs; refill regs for g+2 ----
        // (safe single-buffer: writes after B_b, published at B_c, read after B_c)
        if (g < 3) stagex(bufX, xp);
        if (g < 2) loadx(vg + 2 * VBLK, xp);

        // ---- layer 2 (K=128): act1 -> act2, bias in C, relu ----
        #pragma unroll 2
        for (int nt = 0; nt < 8; ++nt) {
            const u16* rd = act1 + (nt * 16 + l15) * ASTR + qd * 8;
            bf16x8 B2[4];
            #pragma unroll
            for (int kk = 0; kk < 4; ++kk) B2[kk] = *(const bf16x8*)(rd + kk * 32);
            u16* wr = act2 + (nt * 16 + l15) * ASTR + f0 + qd * 4;
            #pragma unroll
            for (int mt = 0; mt < 2; ++mt) {
                f32x4 a = b2f[mt];
                #pragma unroll
                for (int kk = 0; kk < 4; ++kk)
                    a = __builtin_amdgcn_mfma_f32_16x16x32_bf16(w2a[mt][kk], B2[kk], a, 0, 0, 0);
                uint2 s;
                s.x = pk2(fmaxf(a[0], 0.f), fmaxf(a[1], 0.f));
                s.y = pk2(fmaxf(a[2], 0.f), fmaxf(a[3], 0.f));
                *(uint2*)(wr + mt * 16) = s;
            }
        }
        __syncthreads();                   // B_c: act2 AND restaged bufX visible

        // ---- layer 3 (K=128): act2 -> accR via C-chaining ----
        #pragma unroll 1
        for (int nt = 0; nt < 8; ++nt) {
            int sg = sgv[nt];
            const u16* rd = act2 + (nt * 16 + l15) * ASTR + qd * 8;
            bf16x8 B3[4];
            #pragma unroll
            for (int kk = 0; kk < 4; ++kk) B3[kk] = *(const bf16x8*)(rd + kk * 32);
            int first = __builtin_amdgcn_readfirstlane(sg);
            bool uni = (__ballot(sg == first) == ~0ull);
            if (uni) {
                if (first != cur) {
                    if (cntv > 0.f) flush();
                    cur = first;
                }
                #pragma unroll
                for (int mt = 0; mt < 2; ++mt) {
                    f32x4 a = accR[mt];
                    #pragma unroll
                    for (int kk = 0; kk < 4; ++kk)
                        a = __builtin_amdgcn_mfma_f32_16x16x32_bf16(w3a[mt][kk], B3[kk], a, 0, 0, 0);
                    accR[mt] = a;
                }
                cntv += 16.f;
            } else {                       // boundary inside subtile (rare)
                if (cntv > 0.f) flush();
                f32x4 D[2];
                #pragma unroll
                for (int mt = 0; mt < 2; ++mt) {
                    f32x4 a = {0.f, 0.f, 0.f, 0.f};
                    #pragma unroll
                    for (int kk = 0; kk < 4; ++kk)
                        a = __builtin_amdgcn_mfma_f32_16x16x32_bf16(w3a[mt][kk], B3[kk], a, 0, 0, 0);
                    D[mt] = a;
                }
                // segmented inclusive scan over 16 voter lanes (sorted -> masking safe)
                float one = 1.f;
                #pragma unroll
                for (int d = 1; d < 16; d <<= 1) {
                    int so = __shfl_up(sg, d, 16);
                    bool ok = (l15 >= d) && (so == sg);
                    #pragma unroll
                    for (int mt = 0; mt < 2; ++mt)
                        #pragma unroll
                        for (int r = 0; r < 4; ++r) {
                            float o = __shfl_up(D[mt][r], d, 16);
                            if (ok) D[mt][r] += o;
                        }
                    float oc = __shfl_up(one, d, 16);
                    if (ok) one += oc;
                }
                int sgn = __shfl_down(sg, 1, 16);
                bool isend = (l15 == 15) || (sgn != sg);
                if (isend) {
                    float* p = agg + (size_t)sg * EMB + f0 + qd * 4;
                    #pragma unroll
                    for (int mt = 0; mt < 2; ++mt)
                        #pragma unroll
                        for (int r = 0; r < 4; ++r) atomicAdd(p + mt * 16 + r, D[mt][r]);
                    if (wv == 0 && qd == 0) atomicAdd(cntf + sg, one);
                }
                cur = __shfl(sg, 15, 16);  // last voter's run continues
            }
        }
    }
    if (cntv > 0.f) flush();
}

// ---------------- Kernel C: global MLP + log_softmax (fp32) ----------------
// Adds deferred local bias3: agg_true[s][j] = agg[s][j] + cnt[s]*lb3[j].
__global__ void __launch_bounds__(256) global_mlp(
    const float* __restrict__ agg, const float* __restrict__ cntf, const float* __restrict__ lb3,
    const float* __restrict__ gW1, const float* __restrict__ gb1,
    const float* __restrict__ gW2, const float* __restrict__ gb2,
    const float* __restrict__ gW3, const float* __restrict__ gb3,
    float* __restrict__ out)
{
    __shared__ float actA[8 * 128];
    __shared__ float actB[8 * 128];
    __shared__ float sc[8 * 32];
    const int tid = threadIdx.x;
    const int s0 = blockIdx.x * 8;

    #pragma unroll
    for (int i = 0; i < 4; ++i) {
        int f = i * 256 + tid;
        actA[f] = agg[(size_t)s0 * 128 + f] + cntf[s0 + (f >> 7)] * lb3[f & 127];
    }
    __syncthreads();

    const int j = tid & 127, g = tid >> 7;
    {
        float acc[4];
        #pragma unroll
        for (int si = 0; si < 4; ++si) acc[si] = gb1[j];
        #pragma unroll 8
        for (int k = 0; k < 128; ++k) {
            float w = gW1[k * 128 + j];
            #pragma unroll
            for (int si = 0; si < 4; ++si) acc[si] += actA[(g * 4 + si) * 128 + k] * w;
        }
        #pragma unroll
        for (int si = 0; si < 4; ++si) actB[(g * 4 + si) * 128 + j] = fmaxf(acc[si], 0.f);
    }
    __syncthreads();
    {
        float acc[4];
        #pragma unroll
        for (int si = 0; si < 4; ++si) acc[si] = gb2[j];
        #pragma unroll 8
        for (int k = 0; k < 128; ++k) {
            float w = gW2[k * 128 + j];
            #pragma unroll
            for (int si = 0; si < 4; ++si) acc[si] += actB[(g * 4 + si) * 128 + k] * w;
        }
        #pragma unroll
        for (int si = 0; si < 4; ++si) actA[(g * 4 + si) * 128 + j] = fmaxf(acc[si], 0.f);
    }
    __syncthreads();
    {
        int c = tid & 31, sg = tid >> 5;
        float a3 = gb3[c];
        #pragma unroll 8
        for (int k = 0; k < 128; ++k) a3 += actA[sg * 128 + k] * gW3[k * 32 + c];
        sc[sg * 32 + c] = a3;
    }
    __syncthreads();
    {
        int c = tid & 31, sg = tid >> 5;
        float v = sc[sg * 32 + c];
        float m = v;
        #pragma unroll
        for (int off = 16; off >= 1; off >>= 1) m = fmaxf(m, __shfl_xor(m, off, 32));
        float e = expf(v - m);
        float sum = e;
        #pragma unroll
        for (int off = 16; off >= 1; off >>= 1) sum += __shfl_xor(sum, off, 32);
        out[(size_t)(s0 + sg) * 32 + c] = (v - m) - logf(sum);
    }
}

extern "C" void kernel_launch(void* const* d_in, const int* in_sizes, int n_in,
                              void* d_out, int out_size, void* d_ws, size_t ws_size,
                              hipStream_t stream) {
    const float* x   = (const float*)d_in[0];
    const int*   idx = (const int*)d_in[1];
    const float* lW1 = (const float*)d_in[2];
    const float* lb1 = (const float*)d_in[3];
    const float* lW2 = (const float*)d_in[4];
    const float* lb2 = (const float*)d_in[5];
    const float* lW3 = (const float*)d_in[6];
    const float* lb3 = (const float*)d_in[7];
    const float* gW1 = (const float*)d_in[8];
    const float* gb1 = (const float*)d_in[9];
    const float* gW2 = (const float*)d_in[10];
    const float* gb2 = (const float*)d_in[11];
    const float* gW3 = (const float*)d_in[12];
    const float* gb3 = (const float*)d_in[13];
    float* out = (float*)d_out;

    float* agg  = (float*)d_ws;                                 // [4096][128] fp32 = 2 MB
    float* cntf = agg + (size_t)NUM_ELEC * EMB;                 // [4096] fp32
    u16* w1t = (u16*)(cntf + NUM_ELEC);
    u16* w2t = w1t + 128 * 32;
    u16* w3t = w2t + 128 * 128;

    hipMemsetAsync(d_ws, 0, ((size_t)NUM_ELEC * EMB + NUM_ELEC) * sizeof(float), stream);
    prep_weights<<<64, 256, 0, stream>>>(lW1, lW2, lW3, w1t, w2t, w3t);
    local_fused<<<N_VOTERS / 512, 256, 0, stream>>>(x, idx, lb1, lb2, w1t, w2t, w3t, agg, cntf);
    global_mlp<<<NUM_ELEC / 8, 256, 0, stream>>>(agg, cntf, lb3, gW1, gb1, gW2, gb2, gW3, gb3, out);
}

// Round 9
// 302.050 us; speedup vs baseline: 1.2561x; 1.0574x over previous
//
#include <hip/hip_runtime.h>
#include <hip/hip_bf16.h>
#include <math.h>

#define N_VOTERS 1048576
#define NUM_CAND 32
#define EMB 128
#define NUM_ELEC 4096

typedef unsigned short u16;
typedef unsigned int u32;
typedef __attribute__((ext_vector_type(8))) short bf16x8;
typedef __attribute__((ext_vector_type(4))) short short4v;
typedef __attribute__((ext_vector_type(4))) float f32x4;

#if defined(__has_builtin)
#if __has_builtin(__builtin_amdgcn_cvt_pk_bf16_f32)
#define HAVE_CVT_PK_BF16 1
#endif
#endif

__device__ __forceinline__ u16 f2bf(float f) {   // RNE (prep only)
    union { float f; u32 u; } v; v.f = f;
    u32 r = v.u + 0x7FFFu + ((v.u >> 16) & 1u);
    return (u16)(r >> 16);
}
// pack two floats to bf16: f0 -> low16, f1 -> high16.
__device__ __forceinline__ u32 pk2(float f0, float f1) {
#ifdef HAVE_CVT_PK_BF16
    typedef __attribute__((ext_vector_type(2))) __bf16 bf16x2;
    bf16x2 r = __builtin_amdgcn_cvt_pk_bf16_f32(f0, f1);   // lo=cvt(f0), hi=cvt(f1)
    union { bf16x2 v; u32 u; } c; c.v = r;
    return c.u;
#else
    u32 u0 = __float_as_uint(f0) + 0x8000u;
    u32 u1 = __float_as_uint(f1) + 0x8000u;
    return __builtin_amdgcn_perm(u1, u0, 0x07060302u);
#endif
}

// ---------------- Kernel A: transpose+convert local weights to bf16 ----------------
// w1t: [128][32] = W1^T (out-major); w2t/w3t: [128][128] (out-major) — A-frag layout.
__global__ void prep_weights(const float* __restrict__ lW1, const float* __restrict__ lW2,
                             const float* __restrict__ lW3,
                             u16* __restrict__ w1t, u16* __restrict__ w2t, u16* __restrict__ w3t) {
    int tid = blockIdx.x * blockDim.x + threadIdx.x;  // 0..16383
    if (tid < 4096) {
        int n = tid >> 5, k = tid & 31;
        w1t[tid] = f2bf(lW1[k * EMB + n]);
    }
    {
        int n = tid >> 7, k = tid & 127;
        w2t[tid] = f2bf(lW2[k * EMB + n]);
        w3t[tid] = f2bf(lW3[k * EMB + n]);
    }
}

// ---------------- Kernel B: fused local MLP (R10 structure, VERBATIM) -------------------
// 2048 blocks x 256 thr (4 waves). Wave wv owns features wv*32..+31 (2 m-tiles); weights +
// biases loaded ONCE per block into VGPRs (needs the >=160-VGPR budget of
// __launch_bounds__(256,3) — at (256,4) the compiler REMATERIALIZES weight loads per group:
// R9 measured FETCH 68->371 MB, 155->226 us. Do not tighten).
// 8 groups x 64 voters. bufX is DOUBLE-BUFFERED: group g's L2 phase stages bufX for g+1
// from registers prefetched in group g-1, so the act2 barrier also publishes bufX ->
// 2 barriers/group (R10: 155->122 us vs 3 barriers).
// SETTLED ACROSS R11-R18 (do not retry):
//  - direct per-lane global x loads: spills (R11 WRITE 547MB / R12 89MB)
//  - L2+L3 linearity fusion: spills at ANY reg cap (R14 274MB @170, R17 108MB @256)
//  - s_setprio around MFMA: null (R13, lockstep waves)
//  - occupancy changes in EITHER direction: (512,6)=remat (R15), (512,4) 16 waves/CU
//    = 149us (R16, 2x act reads), VBLK=128 @ 8 waves/CU = 136us (R18, less cross-block
//    overlap). 3 blocks/CU x 4 waves is the interior optimum.
// The kernel is LDS-pipe-bound (~79us of LDS busy incl. conflicts vs ~37us MFMA floor);
// act round-trips are irreducible without register state the allocator won't grant.
// Bias1/2 ride the MFMA C operand. Layer-3 C-operand chains the segment sum across
// subtiles AND groups; flush = butterfly over 16 voter lanes + l15==0 atomics. Bias3
// deferred via per-election voter counts.
__global__ __launch_bounds__(256, 3) void local_fused(
    const float* __restrict__ x, const int* __restrict__ idx,
    const float* __restrict__ lb1, const float* __restrict__ lb2,
    const u16* __restrict__ w1t, const u16* __restrict__ w2t, const u16* __restrict__ w3t,
    float* __restrict__ agg, float* __restrict__ cntf)
{
    constexpr int XSTR = 36;   // x tile stride (72B rows, 8B-aligned b64 reads)
    constexpr int ASTR = 136;  // act stride (272B rows, 16B-aligned b128 reads)
    __shared__ __align__(16) u16 bufX[2][64 * XSTR];  // 2 x 4608 B
    __shared__ __align__(16) u16 act1[64 * ASTR];     // 17408 B
    __shared__ __align__(16) u16 act2[64 * ASTR];     // 17408 B  (total 44032)

    const int tid = threadIdx.x;
    const int lane = tid & 63;
    const int wv = tid >> 6;        // feature quarter 0..3
    const int qd = lane >> 4;
    const int l15 = lane & 15;
    const int f0 = wv * 32;
    const int vbase = blockIdx.x * 512;

    // ---- weights + biases resident for the whole block ----
    bf16x8 w1a[2], w2a[2][4], w3a[2][4];
    f32x4 b1f[2], b2f[2];
    #pragma unroll
    for (int mt = 0; mt < 2; ++mt) {
        int mrow = f0 + mt * 16 + l15;
        w1a[mt] = *(const bf16x8*)(w1t + mrow * 32 + qd * 8);
        #pragma unroll
        for (int kk = 0; kk < 4; ++kk) {
            w2a[mt][kk] = *(const bf16x8*)(w2t + mrow * 128 + kk * 32 + qd * 8);
            w3a[mt][kk] = *(const bf16x8*)(w3t + mrow * 128 + kk * 32 + qd * 8);
        }
        b1f[mt] = *(const f32x4*)(lb1 + f0 + mt * 16 + qd * 4);
        b2f[mt] = *(const f32x4*)(lb2 + f0 + mt * 16 + qd * 4);
    }

    // ---- segment state (spans all 8 groups) ----
    f32x4 accR[2];
    #pragma unroll
    for (int mt = 0; mt < 2; ++mt) accR[mt] = (f32x4){0.f, 0.f, 0.f, 0.f};
    float cntv = 0.f;
    int cur = idx[vbase];

    auto flush = [&]() {   // wave-uniform call sites only
        #pragma unroll
        for (int d = 1; d < 16; d <<= 1)
            #pragma unroll
            for (int mt = 0; mt < 2; ++mt)
                #pragma unroll
                for (int r = 0; r < 4; ++r) accR[mt][r] += __shfl_xor(accR[mt][r], d, 16);
        if (l15 == 0) {
            float* p = agg + (size_t)cur * EMB + f0 + qd * 4;
            #pragma unroll
            for (int mt = 0; mt < 2; ++mt)
                #pragma unroll
                for (int r = 0; r < 4; ++r) atomicAdd(p + mt * 16 + r, accR[mt][r]);
            if (wv == 0 && qd == 0) atomicAdd(cntf + cur, cntv);
        }
        #pragma unroll
        for (int mt = 0; mt < 2; ++mt) accR[mt] = (f32x4){0.f, 0.f, 0.f, 0.f};
        cntv = 0.f;
    };

    auto loadx = [&](int v0, uint2* xp) {   // coalesced read + pack of one 64-voter tile
        const float4* xg = (const float4*)(x + (size_t)v0 * NUM_CAND);
        #pragma unroll
        for (int i = 0; i < 2; ++i) {
            float4 v = xg[i * 256 + tid];
            xp[i].x = pk2(v.x, v.y); xp[i].y = pk2(v.z, v.w);
        }
    };
    auto stagex = [&](u16* dst, const uint2* xp) {
        #pragma unroll
        for (int i = 0; i < 2; ++i) {
            int F = i * 256 + tid, row = F >> 3, c4 = (F & 7) * 4;
            *(uint2*)(dst + row * XSTR + c4) = xp[i];
        }
    };

    // ---- prologue: stage group 0, prefetch group 1 into regs ----
    uint2 xp[2];
    loadx(vbase, xp);
    stagex(bufX[0], xp);
    loadx(vbase + 64, xp);
    __syncthreads();                       // initial: bufX[0] visible

    #pragma unroll 1
    for (int g = 0; g < 8; ++g) {
        const int vg = vbase + g * 64;

        // hoist this group's segment ids (latency overlaps L1/L2 compute)
        int sgv[4];
        #pragma unroll
        for (int nt = 0; nt < 4; ++nt) sgv[nt] = idx[vg + nt * 16 + l15];

        // ---- layer 1 (K=32): bufX[g&1] -> act1, bias in C, relu ----
        const u16* bx = bufX[g & 1];
        #pragma unroll
        for (int nt = 0; nt < 4; ++nt) {
            int vr = nt * 16 + l15;
            union { bf16x8 v; short4v h[2]; } b;
            b.h[0] = *(const short4v*)(bx + vr * XSTR + qd * 8);
            b.h[1] = *(const short4v*)(bx + vr * XSTR + qd * 8 + 4);
            u16* wr = act1 + vr * ASTR + f0 + qd * 4;
            #pragma unroll
            for (int mt = 0; mt < 2; ++mt) {
                f32x4 a = __builtin_amdgcn_mfma_f32_16x16x32_bf16(w1a[mt], b.v, b1f[mt], 0, 0, 0);
                uint2 s;
                s.x = pk2(fmaxf(a[0], 0.f), fmaxf(a[1], 0.f));
                s.y = pk2(fmaxf(a[2], 0.f), fmaxf(a[3], 0.f));
                *(uint2*)(wr + mt * 16) = s;
            }
        }
        __syncthreads();                   // B_b: act1 visible

        // ---- stage bufX for g+1 from regs; refill regs for g+2 ----
        if (g < 7) stagex(bufX[(g + 1) & 1], xp);
        if (g < 6) loadx(vg + 128, xp);

        // ---- layer 2 (K=128): act1 -> act2, bias in C, relu ----
        #pragma unroll
        for (int nt = 0; nt < 4; ++nt) {
            const u16* rd = act1 + (nt * 16 + l15) * ASTR + qd * 8;
            bf16x8 B2[4];
            #pragma unroll
            for (int kk = 0; kk < 4; ++kk) B2[kk] = *(const bf16x8*)(rd + kk * 32);
            u16* wr = act2 + (nt * 16 + l15) * ASTR + f0 + qd * 4;
            #pragma unroll
            for (int mt = 0; mt < 2; ++mt) {
                f32x4 a = b2f[mt];
                #pragma unroll
                for (int kk = 0; kk < 4; ++kk)
                    a = __builtin_amdgcn_mfma_f32_16x16x32_bf16(w2a[mt][kk], B2[kk], a, 0, 0, 0);
                uint2 s;
                s.x = pk2(fmaxf(a[0], 0.f), fmaxf(a[1], 0.f));
                s.y = pk2(fmaxf(a[2], 0.f), fmaxf(a[3], 0.f));
                *(uint2*)(wr + mt * 16) = s;
            }
        }
        __syncthreads();                   // B_c: act2 AND bufX[(g+1)&1] visible

        // ---- layer 3 (K=128): act2 -> accR via C-chaining ----
        #pragma unroll 1
        for (int nt = 0; nt < 4; ++nt) {
            int sg = sgv[nt];
            const u16* rd = act2 + (nt * 16 + l15) * ASTR + qd * 8;
            bf16x8 B3[4];
            #pragma unroll
            for (int kk = 0; kk < 4; ++kk) B3[kk] = *(const bf16x8*)(rd + kk * 32);
            int first = __builtin_amdgcn_readfirstlane(sg);
            bool uni = (__ballot(sg == first) == ~0ull);
            if (uni) {
                if (first != cur) {
                    if (cntv > 0.f) flush();
                    cur = first;
                }
                #pragma unroll
                for (int mt = 0; mt < 2; ++mt) {
                    f32x4 a = accR[mt];
                    #pragma unroll
                    for (int kk = 0; kk < 4; ++kk)
                        a = __builtin_amdgcn_mfma_f32_16x16x32_bf16(w3a[mt][kk], B3[kk], a, 0, 0, 0);
                    accR[mt] = a;
                }
                cntv += 16.f;
            } else {                       // boundary inside subtile (rare)
                if (cntv > 0.f) flush();
                f32x4 D[2];
                #pragma unroll
                for (int mt = 0; mt < 2; ++mt) {
                    f32x4 a = {0.f, 0.f, 0.f, 0.f};
                    #pragma unroll
                    for (int kk = 0; kk < 4; ++kk)
                        a = __builtin_amdgcn_mfma_f32_16x16x32_bf16(w3a[mt][kk], B3[kk], a, 0, 0, 0);
                    D[mt] = a;
                }
                // segmented inclusive scan over 16 voter lanes (sorted -> masking safe)
                float one = 1.f;
                #pragma unroll
                for (int d = 1; d < 16; d <<= 1) {
                    int so = __shfl_up(sg, d, 16);
                    bool ok = (l15 >= d) && (so == sg);
                    #pragma unroll
                    for (int mt = 0; mt < 2; ++mt)
                        #pragma unroll
                        for (int r = 0; r < 4; ++r) {
                            float o = __shfl_up(D[mt][r], d, 16);
                            if (ok) D[mt][r] += o;
                        }
                    float oc = __shfl_up(one, d, 16);
                    if (ok) one += oc;
                }
                int sgn = __shfl_down(sg, 1, 16);
                bool isend = (l15 == 15) || (sgn != sg);
                if (isend) {
                    float* p = agg + (size_t)sg * EMB + f0 + qd * 4;
                    #pragma unroll
                    for (int mt = 0; mt < 2; ++mt)
                        #pragma unroll
                        for (int r = 0; r < 4; ++r) atomicAdd(p + mt * 16 + r, D[mt][r]);
                    if (wv == 0 && qd == 0) atomicAdd(cntf + sg, one);
                }
                cur = __shfl(sg, 15, 16);  // last voter's run continues
            }
        }
    }
    if (cntv > 0.f) flush();
}

// ---------------- Kernel C: global MLP + log_softmax (fp32) ----------------
// R19: 512 threads/block (was 256), same 512 blocks x 8 segments. e2e - local_fused has
// been a CONSTANT ~177us across R14-R18 — prep/memset are ~5us, so global_mlp is the
// prime suspect (invisible in top-5 only because ~70 local_fused dispatches outrank it).
// Old config: 8 waves/CU, 128-deep serial k-loops, 4 FMA per latency-exposed weight
// load. New: each 128-lane group handles 2 segs (si<2) instead of 4 -> per-thread work
// halves, waves/CU doubles to 16. Weight loads are L1/L2 broadcast hits; 2x issue count
// is cheap. This doubles TLP on a latency-bound kernel AND diagnoses the 177us: if e2e
// drops well below 300, global_mlp was the elephant; if e2e ~300, the gap is fixed
// overhead and the plateau is real.
// Adds deferred local bias3: agg_true[s][j] = agg[s][j] + cnt[s]*lb3[j].
__global__ void __launch_bounds__(512) global_mlp(
    const float* __restrict__ agg, const float* __restrict__ cntf, const float* __restrict__ lb3,
    const float* __restrict__ gW1, const float* __restrict__ gb1,
    const float* __restrict__ gW2, const float* __restrict__ gb2,
    const float* __restrict__ gW3, const float* __restrict__ gb3,
    float* __restrict__ out)
{
    __shared__ float actA[8 * 128];
    __shared__ float actB[8 * 128];
    __shared__ float sc[8 * 32];
    const int tid = threadIdx.x;
    const int s0 = blockIdx.x * 8;

    #pragma unroll
    for (int i = 0; i < 2; ++i) {
        int f = i * 512 + tid;
        actA[f] = agg[(size_t)s0 * 128 + f] + cntf[s0 + (f >> 7)] * lb3[f & 127];
    }
    __syncthreads();

    const int j = tid & 127, g = tid >> 7;   // g in 0..3, segs g*2 + si
    {
        float acc[2];
        #pragma unroll
        for (int si = 0; si < 2; ++si) acc[si] = gb1[j];
        #pragma unroll 8
        for (int k = 0; k < 128; ++k) {
            float w = gW1[k * 128 + j];
            #pragma unroll
            for (int si = 0; si < 2; ++si) acc[si] += actA[(g * 2 + si) * 128 + k] * w;
        }
        #pragma unroll
        for (int si = 0; si < 2; ++si) actB[(g * 2 + si) * 128 + j] = fmaxf(acc[si], 0.f);
    }
    __syncthreads();
    {
        float acc[2];
        #pragma unroll
        for (int si = 0; si < 2; ++si) acc[si] = gb2[j];
        #pragma unroll 8
        for (int k = 0; k < 128; ++k) {
            float w = gW2[k * 128 + j];
            #pragma unroll
            for (int si = 0; si < 2; ++si) acc[si] += actB[(g * 2 + si) * 128 + k] * w;
        }
        #pragma unroll
        for (int si = 0; si < 2; ++si) actA[(g * 2 + si) * 128 + j] = fmaxf(acc[si], 0.f);
    }
    __syncthreads();
    {
        int c = tid & 31, sg = tid >> 5;     // sg in 0..15; segs 0..7 active
        if (sg < 8) {
            float a3 = gb3[c];
            #pragma unroll 8
            for (int k = 0; k < 128; ++k) a3 += actA[sg * 128 + k] * gW3[k * 32 + c];
            sc[sg * 32 + c] = a3;
        }
    }
    __syncthreads();
    {
        int c = tid & 31, sg = tid >> 5;
        if (sg < 8) {
            float v = sc[sg * 32 + c];
            float m = v;
            #pragma unroll
            for (int off = 16; off >= 1; off >>= 1) m = fmaxf(m, __shfl_xor(m, off, 32));
            float e = expf(v - m);
            float sum = e;
            #pragma unroll
            for (int off = 16; off >= 1; off >>= 1) sum += __shfl_xor(sum, off, 32);
            out[(size_t)(s0 + sg) * 32 + c] = (v - m) - logf(sum);
        }
    }
}

extern "C" void kernel_launch(void* const* d_in, const int* in_sizes, int n_in,
                              void* d_out, int out_size, void* d_ws, size_t ws_size,
                              hipStream_t stream) {
    const float* x   = (const float*)d_in[0];
    const int*   idx = (const int*)d_in[1];
    const float* lW1 = (const float*)d_in[2];
    const float* lb1 = (const float*)d_in[3];
    const float* lW2 = (const float*)d_in[4];
    const float* lb2 = (const float*)d_in[5];
    const float* lW3 = (const float*)d_in[6];
    const float* lb3 = (const float*)d_in[7];
    const float* gW1 = (const float*)d_in[8];
    const float* gb1 = (const float*)d_in[9];
    const float* gW2 = (const float*)d_in[10];
    const float* gb2 = (const float*)d_in[11];
    const float* gW3 = (const float*)d_in[12];
    const float* gb3 = (const float*)d_in[13];
    float* out = (float*)d_out;

    float* agg  = (float*)d_ws;                                 // [4096][128] fp32 = 2 MB
    float* cntf = agg + (size_t)NUM_ELEC * EMB;                 // [4096] fp32
    u16* w1t = (u16*)(cntf + NUM_ELEC);
    u16* w2t = w1t + 128 * 32;
    u16* w3t = w2t + 128 * 128;

    hipMemsetAsync(d_ws, 0, ((size_t)NUM_ELEC * EMB + NUM_ELEC) * sizeof(float), stream);
    prep_weights<<<64, 256, 0, stream>>>(lW1, lW2, lW3, w1t, w2t, w3t);
    local_fused<<<N_VOTERS / 512, 256, 0, stream>>>(x, idx, lb1, lb2, w1t, w2t, w3t, agg, cntf);
    global_mlp<<<NUM_ELEC / 8, 512, 0, stream>>>(agg, cntf, lb3, gW1, gb1, gW2, gb2, gW3, gb3, out);
}